// Round 1
// baseline (15152.148 us; speedup 1.0000x reference)
//
#include <hip/hip_runtime.h>
#include <math.h>

#define EDIM 512
#define HDIM 1024
#define VDIM 32000
#define BDIM 128
#define SDIM 64

// meta int layout in ws:
// [0]=T, [1]=total, [2]=bs_last, [3]=pad
// [4..67]   = bsz[64]
// [68..131] = off[64]
// [132..132+8192) = src_row[r] = t*B + b
#define META_INTS (132 + BDIM * SDIM)

__global__ void meta_kernel(const int* __restrict__ lengths, int* __restrict__ meta) {
    __shared__ int s_bsz[SDIM];
    __shared__ int s_off[SDIM];
    int t = threadIdx.x;  // 64 threads
    int cnt = 0;
    for (int b = 0; b < BDIM; ++b) cnt += (lengths[b] > t) ? 1 : 0;
    s_bsz[t] = cnt;
    __syncthreads();
    if (t == 0) {
        int acc = 0;
        for (int i = 0; i < SDIM; ++i) { s_off[i] = acc; acc += s_bsz[i]; }
        int T = lengths[0];  // sorted descending -> max
        meta[0] = T;
        meta[1] = acc;           // total packed rows
        meta[2] = s_bsz[T - 1];  // bs_last
        meta[3] = 0;
    }
    __syncthreads();
    meta[4 + t] = s_bsz[t];
    meta[68 + t] = s_off[t];
    for (int b = 0; b < s_bsz[t]; ++b) {
        meta[132 + s_off[t] + b] = t * BDIM + b;
    }
}

// Fused LSTM step: gates GEMM (M=128,N=4096,K=K1+H) + cell update.
// Block: 16 batch rows x 32 cells (=> 128 gate columns: i,f,g,o slices).
// grid.x = 256: cn = blockIdx.x & 31, bm = blockIdx.x >> 5
// (cn-major so all bm-tiles of a cn share an XCD -> W slice L2-resident)
template <int K1>
__global__ __launch_bounds__(256) void lstm_step_kernel(
    const float* __restrict__ xsrc,      // layer1: hs0 (T,B,H); layer0: unused
    const float* __restrict__ features,  // layer0 (B,E)
    const int* __restrict__ tokens,      // layer0 (B,S)
    const float* __restrict__ embedW,    // layer0 (V,E)
    const float* __restrict__ w_ih,      // (4H, K1)
    const float* __restrict__ w_hh,      // (4H, H)
    const float* __restrict__ b_ih, const float* __restrict__ b_hh,
    const int* __restrict__ meta,
    float* __restrict__ hs,  // (S,B,H) this layer: reads [t-1], writes [t]
    float* __restrict__ c,   // (B,H)
    int t) {
    const int cn = blockIdx.x & 31;
    const int bm = blockIdx.x >> 5;
    const int tid = threadIdx.x;
    const int KT = K1 + HDIM;
    const int BK = 32;

    __shared__ float As[BK][16];        // As[k][row]
    __shared__ float Ws[BK][128];       // Ws[k][colLocal]
    __shared__ float Gs[16][128];       // gates (post-GEMM)

    const int ty = tid >> 6;   // 0..3  -> rows ty*4..+4
    const int tx = tid & 63;   // cols tx and tx+64
    float acc[4][2] = {};

    const int bsz_t = meta[4 + t];

    for (int kt = 0; kt < KT; kt += BK) {
        // ---- load A tile: 16 rows x 32 k, 2 floats/thread ----
        {
            int r = tid >> 4;            // 0..15
            int kk = (tid & 15) * 2;     // 0..30
            int b = bm * 16 + r;
            int kg = kt + kk;
            float v0, v1;
            if (kg < K1) {
                const float* xp;
                if (K1 == EDIM) {  // layer 0
                    if (t == 0) xp = &features[(size_t)b * EDIM];
                    else xp = &embedW[(size_t)tokens[b * SDIM + (t - 1)] * EDIM];
                } else {           // layer 1
                    xp = &xsrc[((size_t)t * BDIM + b) * HDIM];
                }
                v0 = xp[kg]; v1 = xp[kg + 1];
            } else {
                int kh = kg - K1;
                if (t == 0) { v0 = 0.f; v1 = 0.f; }
                else {
                    const float* hp = &hs[(((size_t)(t - 1)) * BDIM + b) * HDIM];
                    v0 = hp[kh]; v1 = hp[kh + 1];
                }
            }
            As[kk][r] = v0;
            As[kk + 1][r] = v1;
        }
        // ---- load W tile: 128 cols x 32 k, 16 floats/thread ----
        {
            int nl = tid >> 1;              // 0..127
            int kbase = (tid & 1) * 16;     // 0 or 16
            int ng = (nl >> 5) * HDIM + cn * 32 + (nl & 31);
            int kg0 = kt + kbase;
            const float* wp;
            int ko;
            if (kg0 < K1) { wp = &w_ih[(size_t)ng * K1]; ko = kg0; }
            else { wp = &w_hh[(size_t)ng * HDIM]; ko = kg0 - K1; }
#pragma unroll
            for (int q = 0; q < 4; ++q) {
                float4 wv = *(const float4*)(wp + ko + q * 4);
                Ws[kbase + q * 4 + 0][nl] = wv.x;
                Ws[kbase + q * 4 + 1][nl] = wv.y;
                Ws[kbase + q * 4 + 2][nl] = wv.z;
                Ws[kbase + q * 4 + 3][nl] = wv.w;
            }
        }
        __syncthreads();
#pragma unroll
        for (int k = 0; k < BK; ++k) {
            float4 av = *(const float4*)&As[k][ty * 4];
            float w0 = Ws[k][tx];
            float w1 = Ws[k][tx + 64];
            acc[0][0] += av.x * w0; acc[0][1] += av.x * w1;
            acc[1][0] += av.y * w0; acc[1][1] += av.y * w1;
            acc[2][0] += av.z * w0; acc[2][1] += av.z * w1;
            acc[3][0] += av.w * w0; acc[3][1] += av.w * w1;
        }
        __syncthreads();
    }
    // ---- gates -> LDS with bias ----
#pragma unroll
    for (int i = 0; i < 4; ++i) {
#pragma unroll
        for (int j = 0; j < 2; ++j) {
            int nl = tx + j * 64;
            int ng = (nl >> 5) * HDIM + cn * 32 + (nl & 31);
            Gs[ty * 4 + i][nl] = acc[i][j] + b_ih[ng] + b_hh[ng];
        }
    }
    __syncthreads();
    // ---- cell update: 512 cells, 2/thread ----
#pragma unroll
    for (int q = 0; q < 2; ++q) {
        int cc = tid + q * 256;
        int r = cc >> 5;
        int j = cc & 31;
        int b = bm * 16 + r;
        int cell = cn * 32 + j;
        float gi = Gs[r][j];
        float gf = Gs[r][32 + j];
        float gg = Gs[r][64 + j];
        float go = Gs[r][96 + j];
        float i_ = 1.f / (1.f + expf(-gi));
        float f_ = 1.f / (1.f + expf(-gf));
        float g_ = tanhf(gg);
        float o_ = 1.f / (1.f + expf(-go));
        float c_old = (t == 0) ? 0.f : c[(size_t)b * HDIM + cell];
        float c_new = f_ * c_old + i_ * g_;
        float h_new = o_ * tanhf(c_new);
        float h_old = (t == 0) ? 0.f : hs[(((size_t)(t - 1)) * BDIM + b) * HDIM + cell];
        bool active = b < bsz_t;
        float h_out = active ? h_new : h_old;
        hs[((size_t)t * BDIM + b) * HDIM + cell] = h_out;
        if (active) c[(size_t)b * HDIM + cell] = c_new;
    }
}

// Final projection: out[r, :] = hs1[src_row[r], :] @ linW^T + linb, r < total.
// 128x128 tile, BK=16, 256 threads, 8x8 per thread.
__global__ __launch_bounds__(256) void out_gemm_kernel(
    const float* __restrict__ hs1, const float* __restrict__ linW,
    const float* __restrict__ linb, const int* __restrict__ meta,
    float* __restrict__ out) {
    const int total = meta[1];
    const int bm = blockIdx.y;
    const int bn = blockIdx.x;
    if (bm * 128 >= total) return;
    const int tid = threadIdx.x;
    const int tx = tid & 15, ty = tid >> 4;

    __shared__ float As[16][132];
    __shared__ float Bs[16][132];

    float acc[8][8] = {};
    const int* src_row = meta + 132;

    const int arow = tid >> 1;
    const int r_glob = bm * 128 + arow;
    const bool avalid = (r_glob < total);
    const int asrc = avalid ? src_row[r_glob] : 0;
    const int ak8 = (tid & 1) * 8;

    const int nrow = tid >> 1;
    const int bk8 = (tid & 1) * 8;
    const float* bp = &linW[((size_t)bn * 128 + nrow) * HDIM];
    const float* ap = &hs1[(size_t)asrc * HDIM];

    for (int kt = 0; kt < HDIM; kt += 16) {
        {
            float4 v0 = avalid ? *(const float4*)(ap + kt + ak8) : make_float4(0, 0, 0, 0);
            float4 v1 = avalid ? *(const float4*)(ap + kt + ak8 + 4) : make_float4(0, 0, 0, 0);
            As[ak8 + 0][arow] = v0.x; As[ak8 + 1][arow] = v0.y;
            As[ak8 + 2][arow] = v0.z; As[ak8 + 3][arow] = v0.w;
            As[ak8 + 4][arow] = v1.x; As[ak8 + 5][arow] = v1.y;
            As[ak8 + 6][arow] = v1.z; As[ak8 + 7][arow] = v1.w;
        }
        {
            float4 v0 = *(const float4*)(bp + kt + bk8);
            float4 v1 = *(const float4*)(bp + kt + bk8 + 4);
            Bs[bk8 + 0][nrow] = v0.x; Bs[bk8 + 1][nrow] = v0.y;
            Bs[bk8 + 2][nrow] = v0.z; Bs[bk8 + 3][nrow] = v0.w;
            Bs[bk8 + 4][nrow] = v1.x; Bs[bk8 + 5][nrow] = v1.y;
            Bs[bk8 + 6][nrow] = v1.z; Bs[bk8 + 7][nrow] = v1.w;
        }
        __syncthreads();
#pragma unroll
        for (int k = 0; k < 16; ++k) {
            float4 a0 = *(const float4*)&As[k][ty * 8];
            float4 a1 = *(const float4*)&As[k][ty * 8 + 4];
            float4 b0 = *(const float4*)&Bs[k][tx * 8];
            float4 b1 = *(const float4*)&Bs[k][tx * 8 + 4];
            float aa[8] = {a0.x, a0.y, a0.z, a0.w, a1.x, a1.y, a1.z, a1.w};
            float bb[8] = {b0.x, b0.y, b0.z, b0.w, b1.x, b1.y, b1.z, b1.w};
#pragma unroll
            for (int i = 0; i < 8; ++i)
#pragma unroll
                for (int j = 0; j < 8; ++j) acc[i][j] += aa[i] * bb[j];
        }
        __syncthreads();
    }
#pragma unroll
    for (int i = 0; i < 8; ++i) {
        int r = bm * 128 + ty * 8 + i;
        if (r >= total) continue;
        size_t rowoff = (size_t)r * VDIM + bn * 128 + tx * 8;
#pragma unroll
        for (int j = 0; j < 8; ++j) {
            out[rowoff + j] = acc[i][j] + linb[bn * 128 + tx * 8 + j];
        }
    }
}

__global__ void hc_out_kernel(const float* __restrict__ hs0, const float* __restrict__ hs1,
                              const float* __restrict__ c0, const float* __restrict__ c1,
                              const int* __restrict__ meta, float* __restrict__ out) {
    const int total = meta[1];
    const int bs_last = meta[2];
    size_t base = (size_t)total * VDIM;
    int idx = blockIdx.x * 256 + threadIdx.x;  // 2*B*H = 262144
    int l = idx >> 17;
    int b = (idx >> 10) & 127;
    int j = idx & 1023;
    if (b >= bs_last) return;
    const float* hsx = l ? hs1 : hs0;
    const float* cx = l ? c1 : c0;
    float hv = hsx[(((size_t)(SDIM - 1)) * BDIM + b) * HDIM + j];
    float cv = cx[(size_t)b * HDIM + j];
    out[base + ((size_t)l * bs_last + b) * HDIM + j] = hv;
    out[base + (size_t)2 * bs_last * HDIM + ((size_t)l * bs_last + b) * HDIM + j] = cv;
}

extern "C" void kernel_launch(void* const* d_in, const int* in_sizes, int n_in,
                              void* d_out, int out_size, void* d_ws, size_t ws_size,
                              hipStream_t stream) {
    const float* features = (const float*)d_in[0];
    const int* src_tokens = (const int*)d_in[1];
    const int* lengths = (const int*)d_in[2];
    const float* embedW = (const float*)d_in[3];
    const float* w_ih0 = (const float*)d_in[4];
    const float* w_hh0 = (const float*)d_in[5];
    const float* b_ih0 = (const float*)d_in[6];
    const float* b_hh0 = (const float*)d_in[7];
    const float* w_ih1 = (const float*)d_in[8];
    const float* w_hh1 = (const float*)d_in[9];
    const float* b_ih1 = (const float*)d_in[10];
    const float* b_hh1 = (const float*)d_in[11];
    const float* linW = (const float*)d_in[12];
    const float* linb = (const float*)d_in[13];
    float* out = (float*)d_out;

    int* meta = (int*)d_ws;
    size_t meta_bytes = ((size_t)META_INTS * 4 + 255) & ~(size_t)255;
    float* hs0 = (float*)((char*)d_ws + meta_bytes);
    float* hs1 = hs0 + (size_t)SDIM * BDIM * HDIM;
    float* c0 = hs1 + (size_t)SDIM * BDIM * HDIM;
    float* c1 = c0 + (size_t)BDIM * HDIM;

    meta_kernel<<<1, 64, 0, stream>>>(lengths, meta);

    for (int t = 0; t < SDIM; ++t) {
        lstm_step_kernel<EDIM><<<256, 256, 0, stream>>>(
            nullptr, features, src_tokens, embedW,
            w_ih0, w_hh0, b_ih0, b_hh0, meta, hs0, c0, t);
    }
    for (int t = 0; t < SDIM; ++t) {
        lstm_step_kernel<HDIM><<<256, 256, 0, stream>>>(
            hs0, nullptr, nullptr, nullptr,
            w_ih1, w_hh1, b_ih1, b_hh1, meta, hs1, c1, t);
    }

    dim3 g(VDIM / 128, (BDIM * SDIM) / 128);  // 250 x 64
    out_gemm_kernel<<<g, 256, 0, stream>>>(hs1, linW, linb, meta, out);

    hc_out_kernel<<<1024, 256, 0, stream>>>(hs0, hs1, c0, c1, meta, out);
}

// Round 2
// 5606.354 us; speedup vs baseline: 2.7027x; 2.7027x over previous
//
#include <hip/hip_runtime.h>
#include <math.h>

#define EDIM 512
#define HDIM 1024
#define VDIM 32000
#define BDIM 128
#define SDIM 64
#define NG 4096

typedef __bf16 bf16;
typedef bf16 bf16x8 __attribute__((ext_vector_type(8)));
typedef float f32x4 __attribute__((ext_vector_type(4)));

// meta int layout: [0]=T,[1]=total,[2]=bs_last,[3]=pad,[4..67]=bsz,[68..131]=off,
// [132..132+8192)=src_row
#define META_INTS (132 + BDIM * SDIM)

__global__ void meta_kernel(const int* __restrict__ lengths, int* __restrict__ meta) {
    __shared__ int s_bsz[SDIM];
    __shared__ int s_off[SDIM];
    int t = threadIdx.x;  // 64 threads
    int cnt = 0;
    for (int b = 0; b < BDIM; ++b) cnt += (lengths[b] > t) ? 1 : 0;
    s_bsz[t] = cnt;
    __syncthreads();
    if (t == 0) {
        int acc = 0;
        for (int i = 0; i < SDIM; ++i) { s_off[i] = acc; acc += s_bsz[i]; }
        int T = lengths[0];
        meta[0] = T;
        meta[1] = acc;
        meta[2] = s_bsz[T - 1];
        meta[3] = 0;
    }
    __syncthreads();
    meta[4 + t] = s_bsz[t];
    meta[68 + t] = s_off[t];
    for (int b = 0; b < s_bsz[t]; ++b) meta[132 + s_off[t] + b] = t * BDIM + b;
}

// fp32 -> bf16 (RNE), 8 elems/thread
__global__ void cvt_bf16_kernel(const float* __restrict__ src, bf16* __restrict__ dst, int n8) {
    int idx = blockIdx.x * 256 + threadIdx.x;
    if (idx >= n8) return;
    float4 a = ((const float4*)src)[(size_t)idx * 2];
    float4 b = ((const float4*)src)[(size_t)idx * 2 + 1];
    float v[8] = {a.x, a.y, a.z, a.w, b.x, b.y, b.z, b.w};
    bf16x8 o;
#pragma unroll
    for (int i = 0; i < 8; ++i) o[i] = (bf16)v[i];
    *(bf16x8*)(dst + (size_t)idx * 8) = o;
}

// build x0 rows (r = t*B + b) as bf16 hi/lo split
__global__ void gather_x0_kernel(const float* __restrict__ features,
                                 const int* __restrict__ tokens,
                                 const float* __restrict__ embedW,
                                 bf16* __restrict__ xhi, bf16* __restrict__ xlo) {
    int idx = blockIdx.x * 256 + threadIdx.x;  // 8192 * 64
    int r = idx >> 6;
    int c = (idx & 63) * 8;
    int t = r >> 7, b = r & 127;
    const float* src = (t == 0) ? (features + (size_t)b * EDIM)
                                : (embedW + (size_t)tokens[b * SDIM + (t - 1)] * EDIM);
    float4 a = *(const float4*)(src + c);
    float4 d = *(const float4*)(src + c + 4);
    float v[8] = {a.x, a.y, a.z, a.w, d.x, d.y, d.z, d.w};
    bf16x8 hi, lo;
#pragma unroll
    for (int i = 0; i < 8; ++i) {
        hi[i] = (bf16)v[i];
        lo[i] = (bf16)(v[i] - (float)hi[i]);
    }
    size_t o = (size_t)r * EDIM + c;
    *(bf16x8*)(xhi + o) = hi;
    *(bf16x8*)(xlo + o) = lo;
}

// C[M x N] = (Ahi + Alo) @ B^T + bias0 + bias1
// A: M x K bf16 hi/lo (optional row gather). B: N x K bf16. C fp32, ldc.
// Tile 128x128, BK=32, 256 threads = 4 waves (2x2), each wave 64x64.
// LDS layout [kg][row][8 bf16] => 16B frags, 2-way bank aliasing (free).
__global__ __launch_bounds__(256) void gemm_bulk(
    const bf16* __restrict__ Ahi, const bf16* __restrict__ Alo,
    const bf16* __restrict__ Bb, float* __restrict__ C,
    const float* __restrict__ bias0, const float* __restrict__ bias1,
    const int* __restrict__ srcrow, const int* __restrict__ mdyn,
    int M, int K, int ldc) {
    const int Mr = mdyn ? mdyn[0] : M;
    const int bm = blockIdx.x;
    const int bn = blockIdx.y;
    if (bm * 128 >= Mr) return;

    const int tid = threadIdx.x;
    const int wave = tid >> 6, lane = tid & 63;
    const int kg = lane >> 4, rl = lane & 15;
    const int wm = wave >> 1, wn = wave & 1;

    __shared__ bf16 sAhi[4][128][8];
    __shared__ bf16 sAlo[4][128][8];
    __shared__ bf16 sB[4][128][8];

    // staging coords: each thread stages row (tid&127) at kg {tid>>7, tid>>7 + 2}
    const int sr = tid & 127;
    const int skg = tid >> 7;
    int arow_g = bm * 128 + sr;
    int arow = (arow_g < Mr) ? (srcrow ? srcrow[arow_g] : arow_g) : (srcrow ? srcrow[0] : 0);
    const bf16* pAhi = Ahi + (size_t)arow * K + skg * 8;
    const bf16* pAlo = Alo + (size_t)arow * K + skg * 8;
    const bf16* pB = Bb + ((size_t)bn * 128 + sr) * K + skg * 8;

    f32x4 acc[4][4] = {};
    int4 rAh0, rAh1, rAl0, rAl1, rB0, rB1;

#define LOADREGS(KT)                                   \
    {                                                  \
        rAh0 = *(const int4*)(pAhi + (KT));            \
        rAh1 = *(const int4*)(pAhi + (KT) + 16);       \
        rAl0 = *(const int4*)(pAlo + (KT));            \
        rAl1 = *(const int4*)(pAlo + (KT) + 16);       \
        rB0 = *(const int4*)(pB + (KT));               \
        rB1 = *(const int4*)(pB + (KT) + 16);          \
    }

    LOADREGS(0);
    for (int kt = 0; kt < K; kt += 32) {
        *(int4*)&sAhi[skg][sr][0] = rAh0;
        *(int4*)&sAhi[skg + 2][sr][0] = rAh1;
        *(int4*)&sAlo[skg][sr][0] = rAl0;
        *(int4*)&sAlo[skg + 2][sr][0] = rAl1;
        *(int4*)&sB[skg][sr][0] = rB0;
        *(int4*)&sB[skg + 2][sr][0] = rB1;
        __syncthreads();
        if (kt + 32 < K) LOADREGS(kt + 32);

        bf16x8 bfr[4];
#pragma unroll
        for (int nt = 0; nt < 4; ++nt)
            bfr[nt] = *(const bf16x8*)&sB[kg][wn * 64 + nt * 16 + rl][0];
#pragma unroll
        for (int mt = 0; mt < 4; ++mt) {
            bf16x8 ah = *(const bf16x8*)&sAhi[kg][wm * 64 + mt * 16 + rl][0];
            bf16x8 al = *(const bf16x8*)&sAlo[kg][wm * 64 + mt * 16 + rl][0];
#pragma unroll
            for (int nt = 0; nt < 4; ++nt) {
                acc[mt][nt] = __builtin_amdgcn_mfma_f32_16x16x32_bf16(ah, bfr[nt], acc[mt][nt], 0, 0, 0);
                acc[mt][nt] = __builtin_amdgcn_mfma_f32_16x16x32_bf16(al, bfr[nt], acc[mt][nt], 0, 0, 0);
            }
        }
        __syncthreads();
    }
#undef LOADREGS

    // D layout: col = lane&15, row = (lane>>4)*4 + j
#pragma unroll
    for (int nt = 0; nt < 4; ++nt) {
        int gcol = bn * 128 + wn * 64 + nt * 16 + rl;
        float bv = 0.f;
        if (bias0) bv += bias0[gcol];
        if (bias1) bv += bias1[gcol];
#pragma unroll
        for (int mt = 0; mt < 4; ++mt) {
#pragma unroll
            for (int j = 0; j < 4; ++j) {
                int grow = bm * 128 + wm * 64 + mt * 16 + kg * 4 + j;
                if (grow < Mr) C[(size_t)grow * ldc + gcol] = acc[mt][nt][j] + bv;
            }
        }
    }
}

// Per-step recurrent GEMM: gates[128 x 4096] = h_prev @ Whh^T + ig_t
// BM=128 (all M), BN=16, grid 256 blocks, 256 threads = 4 waves, each 32 rows x 16 cols.
__global__ __launch_bounds__(256) void gates_step_kernel(
    const bf16* __restrict__ hhi, const bf16* __restrict__ hlo,
    const bf16* __restrict__ Whh, const float* __restrict__ igt,
    float* __restrict__ gates) {
    const int bn = blockIdx.x;
    const int tid = threadIdx.x;
    const int wave = tid >> 6, lane = tid & 63;
    const int kg = lane >> 4, rl = lane & 15;

    __shared__ bf16 sAhi[4][128][8];
    __shared__ bf16 sAlo[4][128][8];
    __shared__ bf16 sB[4][16][8];

    const int sr = tid & 127;
    const int skg = tid >> 7;
    const bf16* pAhi = hhi + (size_t)sr * HDIM + skg * 8;
    const bf16* pAlo = hlo + (size_t)sr * HDIM + skg * 8;
    // B staging: threads 0..63, one granule each: row = tid&15, kg = tid>>4
    const bf16* pB = Whh + ((size_t)bn * 16 + (tid & 15)) * HDIM + (tid >> 4) * 8;

    f32x4 acc[2] = {};
    int4 rAh0, rAh1, rAl0, rAl1, rB;

#define LOADREGS(KT)                              \
    {                                             \
        rAh0 = *(const int4*)(pAhi + (KT));       \
        rAh1 = *(const int4*)(pAhi + (KT) + 16);  \
        rAl0 = *(const int4*)(pAlo + (KT));       \
        rAl1 = *(const int4*)(pAlo + (KT) + 16);  \
        if (tid < 64) rB = *(const int4*)(pB + (KT)); \
    }

    LOADREGS(0);
    for (int kt = 0; kt < HDIM; kt += 32) {
        *(int4*)&sAhi[skg][sr][0] = rAh0;
        *(int4*)&sAhi[skg + 2][sr][0] = rAh1;
        *(int4*)&sAlo[skg][sr][0] = rAl0;
        *(int4*)&sAlo[skg + 2][sr][0] = rAl1;
        if (tid < 64) *(int4*)&sB[tid >> 4][tid & 15][0] = rB;
        __syncthreads();
        if (kt + 32 < HDIM) LOADREGS(kt + 32);

        bf16x8 bfr = *(const bf16x8*)&sB[kg][rl][0];
#pragma unroll
        for (int mt = 0; mt < 2; ++mt) {
            bf16x8 ah = *(const bf16x8*)&sAhi[kg][wave * 32 + mt * 16 + rl][0];
            bf16x8 al = *(const bf16x8*)&sAlo[kg][wave * 32 + mt * 16 + rl][0];
            acc[mt] = __builtin_amdgcn_mfma_f32_16x16x32_bf16(ah, bfr, acc[mt], 0, 0, 0);
            acc[mt] = __builtin_amdgcn_mfma_f32_16x16x32_bf16(al, bfr, acc[mt], 0, 0, 0);
        }
        __syncthreads();
    }
#undef LOADREGS

#pragma unroll
    for (int mt = 0; mt < 2; ++mt) {
#pragma unroll
        for (int j = 0; j < 4; ++j) {
            int row = wave * 32 + mt * 16 + kg * 4 + j;
            int col = bn * 16 + rl;
            size_t o = (size_t)row * NG + col;
            gates[o] = acc[mt][j] + igt[o];
        }
    }
}

// cell update: h_cur/c update (active rows), emit hs hi/lo for all rows
__global__ void cell_kernel(const float* __restrict__ gates, const int* __restrict__ meta,
                            float* __restrict__ hcur, float* __restrict__ cst,
                            bf16* __restrict__ hhi, bf16* __restrict__ hlo, int t) {
    int idx = blockIdx.x * 256 + threadIdx.x;  // 128*1024
    int b = idx >> 10, j = idx & 1023;
    float gi = gates[(size_t)b * NG + j];
    float gf = gates[(size_t)b * NG + HDIM + j];
    float gg = gates[(size_t)b * NG + 2 * HDIM + j];
    float go = gates[(size_t)b * NG + 3 * HDIM + j];
    float i_ = 1.f / (1.f + expf(-gi));
    float f_ = 1.f / (1.f + expf(-gf));
    float g_ = tanhf(gg);
    float o_ = 1.f / (1.f + expf(-go));
    float c_old = (t == 0) ? 0.f : cst[idx];
    float c_new = f_ * c_old + i_ * g_;
    float h_new = o_ * tanhf(c_new);
    bool active = b < meta[4 + t];
    float h_out = active ? h_new : ((t == 0) ? 0.f : hcur[idx]);
    if (active) {
        hcur[idx] = h_new;
        cst[idx] = c_new;
    }
    bf16 hi = (bf16)h_out;
    hhi[idx] = hi;
    hlo[idx] = (bf16)(h_out - (float)hi);
}

__global__ void hc_out_kernel(const float* __restrict__ h0, const float* __restrict__ h1,
                              const float* __restrict__ c0, const float* __restrict__ c1,
                              const int* __restrict__ meta, float* __restrict__ out) {
    const int total = meta[1];
    const int bs_last = meta[2];
    size_t base = (size_t)total * VDIM;
    int idx = blockIdx.x * 256 + threadIdx.x;  // 2*B*H
    int l = idx >> 17;
    int b = (idx >> 10) & 127;
    int j = idx & 1023;
    if (b >= bs_last) return;
    const float* hx = l ? h1 : h0;
    const float* cx = l ? c1 : c0;
    out[base + ((size_t)l * bs_last + b) * HDIM + j] = hx[(size_t)b * HDIM + j];
    out[base + (size_t)2 * bs_last * HDIM + ((size_t)l * bs_last + b) * HDIM + j] = cx[(size_t)b * HDIM + j];
}

extern "C" void kernel_launch(void* const* d_in, const int* in_sizes, int n_in,
                              void* d_out, int out_size, void* d_ws, size_t ws_size,
                              hipStream_t stream) {
    const float* features = (const float*)d_in[0];
    const int* src_tokens = (const int*)d_in[1];
    const int* lengths = (const int*)d_in[2];
    const float* embedW = (const float*)d_in[3];
    const float* w_ih0 = (const float*)d_in[4];
    const float* w_hh0 = (const float*)d_in[5];
    const float* b_ih0 = (const float*)d_in[6];
    const float* b_hh0 = (const float*)d_in[7];
    const float* w_ih1 = (const float*)d_in[8];
    const float* w_hh1 = (const float*)d_in[9];
    const float* b_ih1 = (const float*)d_in[10];
    const float* b_hh1 = (const float*)d_in[11];
    const float* linW = (const float*)d_in[12];
    const float* linb = (const float*)d_in[13];
    float* out = (float*)d_out;

    char* ws = (char*)d_ws;
    size_t off = 0;
    auto alloc = [&](size_t bytes) -> char* {
        char* p = ws + off;
        off = (off + bytes + 255) & ~(size_t)255;
        return p;
    };
    int* meta = (int*)alloc(META_INTS * 4);
    bf16* wih0b = (bf16*)alloc((size_t)NG * EDIM * 2);
    bf16* whh0b = (bf16*)alloc((size_t)NG * HDIM * 2);
    bf16* wih1b = (bf16*)alloc((size_t)NG * HDIM * 2);
    bf16* whh1b = (bf16*)alloc((size_t)NG * HDIM * 2);
    bf16* linWb = (bf16*)alloc((size_t)VDIM * HDIM * 2);
    bf16* x0hi = (bf16*)alloc((size_t)SDIM * BDIM * EDIM * 2);
    bf16* x0lo = (bf16*)alloc((size_t)SDIM * BDIM * EDIM * 2);
    bf16* hs0hi = (bf16*)alloc((size_t)SDIM * BDIM * HDIM * 2);
    bf16* hs0lo = (bf16*)alloc((size_t)SDIM * BDIM * HDIM * 2);
    bf16* hs1hi = (bf16*)alloc((size_t)SDIM * BDIM * HDIM * 2);
    bf16* hs1lo = (bf16*)alloc((size_t)SDIM * BDIM * HDIM * 2);
    float* hcur0 = (float*)alloc((size_t)BDIM * HDIM * 4);
    float* hcur1 = (float*)alloc((size_t)BDIM * HDIM * 4);
    float* c0 = (float*)alloc((size_t)BDIM * HDIM * 4);
    float* c1 = (float*)alloc((size_t)BDIM * HDIM * 4);
    bf16* hzero = (bf16*)alloc((size_t)BDIM * HDIM * 2);
    float* gates = (float*)alloc((size_t)BDIM * NG * 4);
    float* ig = (float*)alloc((size_t)SDIM * BDIM * NG * 4);

    hipMemsetAsync((void*)hzero, 0, (size_t)BDIM * HDIM * 2, stream);
    meta_kernel<<<1, 64, 0, stream>>>(lengths, meta);

    // weight conversions
    cvt_bf16_kernel<<<(NG * EDIM / 8 + 255) / 256, 256, 0, stream>>>(w_ih0, wih0b, NG * EDIM / 8);
    cvt_bf16_kernel<<<(NG * HDIM / 8 + 255) / 256, 256, 0, stream>>>(w_hh0, whh0b, NG * HDIM / 8);
    cvt_bf16_kernel<<<(NG * HDIM / 8 + 255) / 256, 256, 0, stream>>>(w_ih1, wih1b, NG * HDIM / 8);
    cvt_bf16_kernel<<<(NG * HDIM / 8 + 255) / 256, 256, 0, stream>>>(w_hh1, whh1b, NG * HDIM / 8);
    cvt_bf16_kernel<<<(VDIM * HDIM / 8 + 255) / 256, 256, 0, stream>>>(linW, linWb, VDIM * HDIM / 8);

    gather_x0_kernel<<<(SDIM * BDIM * EDIM / 8) / 256, 256, 0, stream>>>(
        features, src_tokens, embedW, x0hi, x0lo);

    // ig0 = x0 @ w_ih0^T + b_ih0 + b_hh0   (M=8192, K=512, N=4096)
    gemm_bulk<<<dim3(SDIM * BDIM / 128, NG / 128), 256, 0, stream>>>(
        x0hi, x0lo, wih0b, ig, b_ih0, b_hh0, nullptr, nullptr, SDIM * BDIM, EDIM, NG);

    const size_t BH = (size_t)BDIM * HDIM;
    for (int t = 0; t < SDIM; ++t) {
        const bf16* hh = (t == 0) ? hzero : hs0hi + (size_t)(t - 1) * BH;
        const bf16* hl = (t == 0) ? hzero : hs0lo + (size_t)(t - 1) * BH;
        gates_step_kernel<<<256, 256, 0, stream>>>(hh, hl, whh0b, ig + (size_t)t * BDIM * NG, gates);
        cell_kernel<<<BDIM * HDIM / 256, 256, 0, stream>>>(
            gates, meta, hcur0, c0, hs0hi + (size_t)t * BH, hs0lo + (size_t)t * BH, t);
    }

    // ig1 = hs0 @ w_ih1^T + b_ih1 + b_hh1   (M=8192, K=1024, N=4096)
    gemm_bulk<<<dim3(SDIM * BDIM / 128, NG / 128), 256, 0, stream>>>(
        hs0hi, hs0lo, wih1b, ig, b_ih1, b_hh1, nullptr, nullptr, SDIM * BDIM, HDIM, NG);

    for (int t = 0; t < SDIM; ++t) {
        const bf16* hh = (t == 0) ? hzero : hs1hi + (size_t)(t - 1) * BH;
        const bf16* hl = (t == 0) ? hzero : hs1lo + (size_t)(t - 1) * BH;
        gates_step_kernel<<<256, 256, 0, stream>>>(hh, hl, whh1b, ig + (size_t)t * BDIM * NG, gates);
        cell_kernel<<<BDIM * HDIM / 256, 256, 0, stream>>>(
            gates, meta, hcur1, c1, hs1hi + (size_t)t * BH, hs1lo + (size_t)t * BH, t);
    }

    // out[r,:] = hs1[src_row[r],:] @ linW^T + linb, r < total (M dyn, K=1024, N=32000)
    gemm_bulk<<<dim3(SDIM * BDIM / 128, VDIM / 128), 256, 0, stream>>>(
        hs1hi, hs1lo, linWb, out, linb, nullptr, meta + 132, meta + 1, SDIM * BDIM, HDIM, VDIM);

    hc_out_kernel<<<(2 * BDIM * HDIM) / 256, 256, 0, stream>>>(hcur0, hcur1, c0, c1, meta, out);
}